// Round 2
// baseline (809.940 us; speedup 1.0000x reference)
//
#include <hip/hip_runtime.h>
#include <hip/hip_bf16.h>

// Fused 24-step LSTM forecaster, MI355X gfx950 — round 2.
// fc_in folded into LSTM input weights (W_c = W_ih @ W_in, computed by a setup
// kernel into d_ws). One GEMM per step over K=80 = [X(41)|pad7|h(32)]:
// 2x mfma 16x16x32_bf16 + 1x mfma 16x16x16_bf16. Gate columns permuted so each
// lane owns hid pair (2*c0, 2*c0+1) -> packed b32 h-writes. Prediction via a
// 9th MFMA (h @ W_out^T) instead of a shuffle reduction. Wave-private LDS,
// no barriers in the time loop.

#define BN     512
#define HISTN  24
#define CNN    184
#define FN     17
#define PREDN  24
#define CELLS  (BN * CNN)          // 94208 cells, 64/block -> 1472 blocks
#define FROW   (CNN * FN)          // 3128 floats per (b,t) feature row
#define PMROW  (HISTN * CNN)       // 4416 floats per b in pm25
#define ZSTR   88                  // Zs row stride (shorts): 176B = 44 words, 44%32=12 -> max 2-way (free)
#define WCW    48                  // W_c row stride in ws (floats)

typedef __attribute__((ext_vector_type(8))) short  s8v;
typedef __attribute__((ext_vector_type(4))) short  s4v;
typedef __attribute__((ext_vector_type(4))) float  f4v;

#define MFMA32(a, b, c) __builtin_amdgcn_mfma_f32_16x16x32_bf16(a, b, c, 0, 0, 0)
#define MFMA16(a, b, c) __builtin_amdgcn_mfma_f32_16x16x16bf16_1k(a, b, c, 0, 0, 0)

__device__ __forceinline__ short f2bf(float f) {
  union { float f; unsigned u; } v; v.f = f;
  unsigned r = v.u + 0x7fffu + ((v.u >> 16) & 1u);   // RNE
  return (short)(r >> 16);
}
__device__ __forceinline__ unsigned pack_bf2(float a, float b) {
  union { __hip_bfloat162 h; unsigned u; } v;
  v.h = __float22bfloat162_rn(make_float2(a, b));    // a -> low 16, b -> high 16
  return v.u;
}
__device__ __forceinline__ float fast_sigmoid(float x) {
  float e = __expf(-x);
  return __builtin_amdgcn_rcpf(1.0f + e);
}
__device__ __forceinline__ float fast_tanh(float x) {
  float e = __expf(2.0f * x);
  return 1.0f - 2.0f * __builtin_amdgcn_rcpf(1.0f + e);
}

// ---- setup: W_c = W_ih @ W_in  (128 x 48, cols 41..47 zero), combined bias ----
__global__ void setup_wc(const float* __restrict__ W_in, const float* __restrict__ b_in,
                         const float* __restrict__ W_ih, const float* __restrict__ b_ih,
                         const float* __restrict__ b_hh, float* __restrict__ ws) {
  const int idx = blockIdx.x * 256 + threadIdx.x;
  if (idx < 128 * WCW) {
    const int g = idx / WCW, k = idx % WCW;
    float s = 0.f;
    if (k < 41) {
      #pragma unroll
      for (int j = 0; j < 32; j++) s += W_ih[g * 32 + j] * W_in[j * 41 + k];
    }
    ws[idx] = s;
  } else if (idx < 128 * WCW + 128) {
    const int g = idx - 128 * WCW;
    float s = b_ih[g] + b_hh[g];
    #pragma unroll
    for (int j = 0; j < 32; j++) s += W_ih[g * 32 + j] * b_in[j];
    ws[128 * WCW + g] = s;
  }
}

__global__ __launch_bounds__(256, 4)
void lstm_fused(const float* __restrict__ pm25,
                const float* __restrict__ feat,
                const float* __restrict__ W_hh,
                const float* __restrict__ W_out, const float* __restrict__ b_out,
                const float* __restrict__ ws,
                float* __restrict__ out)
{
  // Zs row: [0..40]=X window+feat, [41..47]=zero, [48..79]=h (natural hid order), [80..87]=pad
  __shared__ __align__(16) short Zs[64][ZSTR];
  __shared__ short buf[64][48];    // [xn0(24) | preds(24)] per cell

  const int tid   = threadIdx.x;
  const int w     = tid >> 6;
  const int lane  = tid & 63;
  const int q     = lane >> 4;
  const int c0    = lane & 15;
  const int mb    = w << 4;
  const int cell0 = blockIdx.x << 6;

  const float* wc = ws;                 // [128][48]
  const float* wb = ws + 128 * WCW;     // [128] combined bias

  // ---------------- loop-invariant weight fragments (registers) -------------
  // Column permutation: tile nt, col c0 -> gate row g = (nt>>1)*32 + 2*c0 + (nt&1).
  s8v WzA[8], WzB[8]; s4v WzC[8];
  #pragma unroll
  for (int nt = 0; nt < 8; nt++) {
    const int g = ((nt >> 1) << 5) + (c0 << 1) + (nt & 1);
    s8v f0, f1;
    #pragma unroll
    for (int j = 0; j < 8; j++) {
      const int k0 = q * 8 + j;              // k 0..31  -> W_c
      f0[j] = f2bf(wc[g * WCW + k0]);
      const int k1 = 32 + q * 8 + j;         // k 32..63 -> W_c tail / zeros / W_hh[:,0..15]
      const float v = (k1 < 48) ? wc[g * WCW + k1] : W_hh[g * 32 + (k1 - 48)];
      f1[j] = f2bf(v);
    }
    WzA[nt] = f0; WzB[nt] = f1;
    s4v f2;                                  // k 64..79 -> W_hh[:,16..31] (16x16x16)
    #pragma unroll
    for (int j = 0; j < 4; j++) f2[j] = f2bf(W_hh[g * 32 + 16 + q * 4 + j]);
    WzC[nt] = f2;
  }
  s8v WoB;                                   // pred MFMA B: col0 = W_out, rest 0
  #pragma unroll
  for (int j = 0; j < 8; j++) WoB[j] = (c0 == 0) ? f2bf(W_out[q * 8 + j]) : (short)0;

  float bi[2], bfg[2], bgg[2], bog[2];
  #pragma unroll
  for (int s = 0; s < 2; s++) {
    const int g = (c0 << 1) + s;
    bi[s]  = wb[g];
    bfg[s] = wb[32 + g];
    bgg[s] = wb[64 + g];
    bog[s] = wb[96 + g];
  }
  const float bout = b_out[0];
  f4v pinit;
  #pragma unroll
  for (int r = 0; r < 4; r++) pinit[r] = (c0 == 0) ? bout : 0.f;

  // ---------------- per-thread staging role ---------------------------------
  const int cl   = mb + (lane >> 2);
  const int sub  = lane & 3;
  const int sub6 = sub * 6, sub4 = sub * 4;
  const int cg   = cell0 + cl;
  const int bb   = cg / CNN, cc = cg % CNN;
  const float* featBase = feat + ((size_t)(bb * 48 + HISTN)) * FROW + cc * FN;
  const float* src = pm25 + bb * PMROW + cc * HISTN;

  // xn window in 3 packed-bf16 regs (positions sub6..sub6+5); also fill buf
  unsigned w0 = pack_bf2(src[sub6 + 0], src[sub6 + 1]);
  unsigned w1 = pack_bf2(src[sub6 + 2], src[sub6 + 3]);
  unsigned w2 = pack_bf2(src[sub6 + 4], src[sub6 + 5]);
  *(unsigned*)&buf[cl][sub6 + 0] = w0;
  *(unsigned*)&buf[cl][sub6 + 2] = w1;
  *(unsigned*)&buf[cl][sub6 + 4] = w2;

  // zero pad k=41..47 and h region k=48..79
  Zs[cl][41 + sub] = 0;
  if (sub < 3) Zs[cl][45 + sub] = 0;
  { s8v zz = 0; *(s8v*)&Zs[cl][48 + sub * 8] = zz; }

  int outB[4], outC[4];
  #pragma unroll
  for (int r = 0; r < 4; r++) {
    const int cgr = cell0 + mb + (q << 2) + r;
    outB[r] = cgr / CNN;
    outC[r] = cgr % CNN;
  }

  float cst[2][4];                  // cell state for hid 2*c0+s, row mb+q*4+r
  #pragma unroll
  for (int s = 0; s < 2; s++)
    #pragma unroll
    for (int r = 0; r < 4; r++) cst[s][r] = 0.f;

  // feature prefetch (one step ahead); sub0..2: 4 vals, sub3: 5 vals
  float fv[5];
  #pragma unroll
  for (int i = 0; i < 5; i++)
    if (i < 4 || sub == 3) fv[i] = featBase[sub4 + i];

  #pragma unroll 1
  for (int t = 0; t < PREDN; t++) {
    // ---- stage X window (3 b32) + features (2 b32 [+1 b16]) ----
    *(unsigned*)&Zs[cl][sub6 + 0] = w0;
    *(unsigned*)&Zs[cl][sub6 + 2] = w1;
    *(unsigned*)&Zs[cl][sub6 + 4] = w2;
    *(unsigned*)&Zs[cl][24 + sub4 + 0] = pack_bf2(fv[0], fv[1]);
    *(unsigned*)&Zs[cl][24 + sub4 + 2] = pack_bf2(fv[2], fv[3]);
    if (sub == 3) Zs[cl][40] = f2bf(fv[4]);
    if (t < PREDN - 1) {
      const float* p = featBase + (size_t)(t + 1) * FROW;
      #pragma unroll
      for (int i = 0; i < 5; i++)
        if (i < 4 || sub == 3) fv[i] = p[sub4 + i];
    }

    // ---- single GEMM: gates = [X|h] @ [W_c ; W_hh]^T ----
    const short* zrow = &Zs[mb + c0][0];
    const s8v za = *(const s8v*)&zrow[q * 8];
    const s8v zb = *(const s8v*)&zrow[32 + q * 8];
    const s4v zc = *(const s4v*)&zrow[64 + q * 4];
    f4v acc[8];
    #pragma unroll
    for (int nt = 0; nt < 8; nt++) {
      f4v a = {0.f, 0.f, 0.f, 0.f};
      a = MFMA32(za, WzA[nt], a);
      a = MFMA32(zb, WzB[nt], a);
      a = MFMA16(zc, WzC[nt], a);
      acc[nt] = a;
    }

    // ---- epilogue: activations, state update ----
    float hv0[4], hv1[4];
    #pragma unroll
    for (int s = 0; s < 2; s++) {
      #pragma unroll
      for (int r = 0; r < 4; r++) {
        const float iv = fast_sigmoid(acc[0 + s][r] + bi[s]);
        const float ff = fast_sigmoid(acc[2 + s][r] + bfg[s]);
        const float gv = fast_tanh   (acc[4 + s][r] + bgg[s]);
        const float ov = fast_sigmoid(acc[6 + s][r] + bog[s]);
        const float cn = ff * cst[s][r] + iv * gv;
        cst[s][r] = cn;
        const float hv = ov * fast_tanh(cn);
        if (s == 0) hv0[r] = hv; else hv1[r] = hv;
      }
    }
    // h pair (hid 2*c0, 2*c0+1) -> one b32 per row
    #pragma unroll
    for (int r = 0; r < 4; r++) {
      const int m = mb + (q << 2) + r;
      *(unsigned*)&Zs[m][48 + (c0 << 1)] = pack_bf2(hv0[r], hv1[r]);
    }

    // ---- pred = h @ W_out^T + b_out via one MFMA (col 0 only) ----
    const s8v zh = *(const s8v*)&zrow[48 + q * 8];
    const f4v pacc = MFMA32(zh, WoB, pinit);
    if (c0 == 0) {
      #pragma unroll
      for (int r = 0; r < 4; r++) {
        out[(outB[r] * PREDN + t) * CNN + outC[r]] = pacc[r];
        buf[mb + (q << 2) + r][24 + t] = f2bf(pacc[r]);
      }
    }

    // ---- slide window: 1 new element from buf ----
    const short nb = buf[cl][t + 6 + sub6];
    w0 = (w0 >> 16) | (w1 << 16);
    w1 = (w1 >> 16) | (w2 << 16);
    w2 = (w2 >> 16) | ((unsigned)(unsigned short)nb << 16);
  }
}

extern "C" void kernel_launch(void* const* d_in, const int* in_sizes, int n_in,
                              void* d_out, int out_size, void* d_ws, size_t ws_size,
                              hipStream_t stream) {
  (void)in_sizes; (void)n_in; (void)out_size; (void)ws_size;
  const float* pm25  = (const float*)d_in[0];
  const float* feat  = (const float*)d_in[1];
  // d_in[2] = time_feature (unused)
  const float* W_in  = (const float*)d_in[3];
  const float* b_in  = (const float*)d_in[4];
  const float* W_ih  = (const float*)d_in[5];
  const float* W_hh  = (const float*)d_in[6];
  const float* b_ih  = (const float*)d_in[7];
  const float* b_hh  = (const float*)d_in[8];
  const float* W_out = (const float*)d_in[9];
  const float* b_out = (const float*)d_in[10];
  float* ws  = (float*)d_ws;    // needs 128*48+128 floats = 25 KB
  float* out = (float*)d_out;

  setup_wc<<<dim3(25), dim3(256), 0, stream>>>(W_in, b_in, W_ih, b_ih, b_hh, ws);
  lstm_fused<<<dim3(CELLS / 64), dim3(256), 0, stream>>>(
      pm25, feat, W_hh, W_out, b_out, ws, out);
}

// Round 3
// 526.970 us; speedup vs baseline: 1.5370x; 1.5370x over previous
//
#include <hip/hip_runtime.h>
#include <hip/hip_bf16.h>

// Fused 24-step LSTM forecaster, MI355X gfx950 — round 3.
// R2 structure (fc_in folded: W_c = W_ih @ W_in via setup kernel; single GEMM
// per step over K=80 = [X(41)|pad7|h(32)] as 2x mfma16x16x32 + 1x 16x16x16;
// pred via a 9th MFMA) with the R2 spill bug fixed: __launch_bounds__(256,2)
// gives the ~170 live VGPRs (84 of loop-invariant weight fragments) room.
// R2's (256,4) capped at 128 VGPR -> weights spilled to scratch -> 770 MB of
// spill traffic per dispatch (FETCH 598 MB / WRITE 250 MB) and 494 us.

#define BN     512
#define HISTN  24
#define CNN    184
#define FN     17
#define PREDN  24
#define CELLS  (BN * CNN)          // 94208 cells, 64/block -> 1472 blocks
#define FROW   (CNN * FN)          // 3128 floats per (b,t) feature row
#define PMROW  (HISTN * CNN)       // 4416 floats per b in pm25
#define ZSTR   88                  // Zs row stride (shorts): 176B -> max 2-way bank alias (free)
#define WCW    48                  // W_c row stride in ws (floats)

typedef __attribute__((ext_vector_type(8))) short  s8v;
typedef __attribute__((ext_vector_type(4))) short  s4v;
typedef __attribute__((ext_vector_type(4))) float  f4v;

#define MFMA32(a, b, c) __builtin_amdgcn_mfma_f32_16x16x32_bf16(a, b, c, 0, 0, 0)
#define MFMA16(a, b, c) __builtin_amdgcn_mfma_f32_16x16x16bf16_1k(a, b, c, 0, 0, 0)

__device__ __forceinline__ short f2bf(float f) {
  union { float f; unsigned u; } v; v.f = f;
  unsigned r = v.u + 0x7fffu + ((v.u >> 16) & 1u);   // RNE
  return (short)(r >> 16);
}
__device__ __forceinline__ unsigned pack_bf2(float a, float b) {
  union { __hip_bfloat162 h; unsigned u; } v;
  v.h = __float22bfloat162_rn(make_float2(a, b));    // a -> low 16, b -> high 16
  return v.u;
}
__device__ __forceinline__ float fast_sigmoid(float x) {
  float e = __expf(-x);
  return __builtin_amdgcn_rcpf(1.0f + e);
}
__device__ __forceinline__ float fast_tanh(float x) {
  float e = __expf(2.0f * x);
  return 1.0f - 2.0f * __builtin_amdgcn_rcpf(1.0f + e);
}

// ---- setup: W_c = W_ih @ W_in  (128 x 48, cols 41..47 zero), combined bias ----
__global__ void setup_wc(const float* __restrict__ W_in, const float* __restrict__ b_in,
                         const float* __restrict__ W_ih, const float* __restrict__ b_ih,
                         const float* __restrict__ b_hh, float* __restrict__ ws) {
  const int idx = blockIdx.x * 256 + threadIdx.x;
  if (idx < 128 * WCW) {
    const int g = idx / WCW, k = idx % WCW;
    float s = 0.f;
    if (k < 41) {
      #pragma unroll
      for (int j = 0; j < 32; j++) s += W_ih[g * 32 + j] * W_in[j * 41 + k];
    }
    ws[idx] = s;
  } else if (idx < 128 * WCW + 128) {
    const int g = idx - 128 * WCW;
    float s = b_ih[g] + b_hh[g];
    #pragma unroll
    for (int j = 0; j < 32; j++) s += W_ih[g * 32 + j] * b_in[j];
    ws[128 * WCW + g] = s;
  }
}

__global__ __launch_bounds__(256, 2)   // (256,4) spilled 84 weight VGPRs -> 770MB scratch traffic
void lstm_fused(const float* __restrict__ pm25,
                const float* __restrict__ feat,
                const float* __restrict__ W_hh,
                const float* __restrict__ W_out, const float* __restrict__ b_out,
                const float* __restrict__ ws,
                float* __restrict__ out)
{
  // Zs row: [0..40]=X window+feat, [41..47]=zero, [48..79]=h, [80..87]=pad
  __shared__ __align__(16) short Zs[64][ZSTR];
  __shared__ short buf[64][48];    // [xn0(24) | preds(24)] per cell

  const int tid   = threadIdx.x;
  const int w     = tid >> 6;
  const int lane  = tid & 63;
  const int q     = lane >> 4;
  const int c0    = lane & 15;
  const int mb    = w << 4;
  const int cell0 = blockIdx.x << 6;

  const float* wc = ws;                 // [128][48]
  const float* wb = ws + 128 * WCW;     // [128] combined bias

  // ---------------- loop-invariant weight fragments (registers) -------------
  // Column permutation: tile nt, col c0 -> gate row g = (nt>>1)*32 + 2*c0 + (nt&1).
  s8v WzA[8], WzB[8]; s4v WzC[8];
  #pragma unroll
  for (int nt = 0; nt < 8; nt++) {
    const int g = ((nt >> 1) << 5) + (c0 << 1) + (nt & 1);
    s8v f0, f1;
    #pragma unroll
    for (int j = 0; j < 8; j++) {
      const int k0 = q * 8 + j;              // k 0..31  -> W_c
      f0[j] = f2bf(wc[g * WCW + k0]);
      const int k1 = 32 + q * 8 + j;         // k 32..63 -> W_c tail / W_hh[:,0..15]
      const float v = (k1 < 48) ? wc[g * WCW + k1] : W_hh[g * 32 + (k1 - 48)];
      f1[j] = f2bf(v);
    }
    WzA[nt] = f0; WzB[nt] = f1;
    s4v f2;                                  // k 64..79 -> W_hh[:,16..31] (16x16x16)
    #pragma unroll
    for (int j = 0; j < 4; j++) f2[j] = f2bf(W_hh[g * 32 + 16 + q * 4 + j]);
    WzC[nt] = f2;
  }
  s8v WoB;                                   // pred MFMA B: col0 = W_out, rest 0
  #pragma unroll
  for (int j = 0; j < 8; j++) WoB[j] = (c0 == 0) ? f2bf(W_out[q * 8 + j]) : (short)0;

  float bi[2], bfg[2], bgg[2], bog[2];
  #pragma unroll
  for (int s = 0; s < 2; s++) {
    const int g = (c0 << 1) + s;
    bi[s]  = wb[g];
    bfg[s] = wb[32 + g];
    bgg[s] = wb[64 + g];
    bog[s] = wb[96 + g];
  }
  const float bout = b_out[0];
  f4v pinit;
  #pragma unroll
  for (int r = 0; r < 4; r++) pinit[r] = (c0 == 0) ? bout : 0.f;

  // ---------------- per-thread staging role ---------------------------------
  const int cl   = mb + (lane >> 2);
  const int sub  = lane & 3;
  const int sub6 = sub * 6, sub4 = sub * 4;
  const int cg   = cell0 + cl;
  const int bb   = cg / CNN, cc = cg % CNN;
  const float* featBase = feat + ((size_t)(bb * 48 + HISTN)) * FROW + cc * FN;
  const float* src = pm25 + bb * PMROW + cc * HISTN;

  // xn window in 3 packed-bf16 regs (positions sub6..sub6+5); also fill buf
  unsigned w0 = pack_bf2(src[sub6 + 0], src[sub6 + 1]);
  unsigned w1 = pack_bf2(src[sub6 + 2], src[sub6 + 3]);
  unsigned w2 = pack_bf2(src[sub6 + 4], src[sub6 + 5]);
  *(unsigned*)&buf[cl][sub6 + 0] = w0;
  *(unsigned*)&buf[cl][sub6 + 2] = w1;
  *(unsigned*)&buf[cl][sub6 + 4] = w2;

  // zero pad k=41..47 and h region k=48..79
  Zs[cl][41 + sub] = 0;
  if (sub < 3) Zs[cl][45 + sub] = 0;
  { s8v zz = 0; *(s8v*)&Zs[cl][48 + sub * 8] = zz; }

  int outB[4], outC[4];
  #pragma unroll
  for (int r = 0; r < 4; r++) {
    const int cgr = cell0 + mb + (q << 2) + r;
    outB[r] = cgr / CNN;
    outC[r] = cgr % CNN;
  }

  float cst[2][4];                  // cell state for hid 2*c0+s, row mb+q*4+r
  #pragma unroll
  for (int s = 0; s < 2; s++)
    #pragma unroll
    for (int r = 0; r < 4; r++) cst[s][r] = 0.f;

  // feature prefetch (one step ahead); sub0..2: 4 vals, sub3: 5 vals
  float fv[5];
  #pragma unroll
  for (int i = 0; i < 5; i++)
    if (i < 4 || sub == 3) fv[i] = featBase[sub4 + i];

  #pragma unroll 1
  for (int t = 0; t < PREDN; t++) {
    // ---- stage X window (3 b32) + features (2 b32 [+1 b16]) ----
    *(unsigned*)&Zs[cl][sub6 + 0] = w0;
    *(unsigned*)&Zs[cl][sub6 + 2] = w1;
    *(unsigned*)&Zs[cl][sub6 + 4] = w2;
    *(unsigned*)&Zs[cl][24 + sub4 + 0] = pack_bf2(fv[0], fv[1]);
    *(unsigned*)&Zs[cl][24 + sub4 + 2] = pack_bf2(fv[2], fv[3]);
    if (sub == 3) Zs[cl][40] = f2bf(fv[4]);
    if (t < PREDN - 1) {
      const float* p = featBase + (size_t)(t + 1) * FROW;
      #pragma unroll
      for (int i = 0; i < 5; i++)
        if (i < 4 || sub == 3) fv[i] = p[sub4 + i];
    }

    // ---- single GEMM: gates = [X|h] @ [W_c ; W_hh]^T ----
    const short* zrow = &Zs[mb + c0][0];
    const s8v za = *(const s8v*)&zrow[q * 8];
    const s8v zb = *(const s8v*)&zrow[32 + q * 8];
    const s4v zc = *(const s4v*)&zrow[64 + q * 4];
    f4v acc[8];
    #pragma unroll
    for (int nt = 0; nt < 8; nt++) {
      f4v a = {0.f, 0.f, 0.f, 0.f};
      a = MFMA32(za, WzA[nt], a);
      a = MFMA32(zb, WzB[nt], a);
      a = MFMA16(zc, WzC[nt], a);
      acc[nt] = a;
    }

    // ---- epilogue: activations, state update ----
    float hv0[4], hv1[4];
    #pragma unroll
    for (int s = 0; s < 2; s++) {
      #pragma unroll
      for (int r = 0; r < 4; r++) {
        const float iv = fast_sigmoid(acc[0 + s][r] + bi[s]);
        const float ff = fast_sigmoid(acc[2 + s][r] + bfg[s]);
        const float gv = fast_tanh   (acc[4 + s][r] + bgg[s]);
        const float ov = fast_sigmoid(acc[6 + s][r] + bog[s]);
        const float cn = ff * cst[s][r] + iv * gv;
        cst[s][r] = cn;
        const float hv = ov * fast_tanh(cn);
        if (s == 0) hv0[r] = hv; else hv1[r] = hv;
      }
    }
    // h pair (hid 2*c0, 2*c0+1) -> one b32 per row
    #pragma unroll
    for (int r = 0; r < 4; r++) {
      const int m = mb + (q << 2) + r;
      *(unsigned*)&Zs[m][48 + (c0 << 1)] = pack_bf2(hv0[r], hv1[r]);
    }

    // ---- pred = h @ W_out^T + b_out via one MFMA (col 0 only) ----
    const s8v zh = *(const s8v*)&zrow[48 + q * 8];
    const f4v pacc = MFMA32(zh, WoB, pinit);
    if (c0 == 0) {
      #pragma unroll
      for (int r = 0; r < 4; r++) {
        out[(outB[r] * PREDN + t) * CNN + outC[r]] = pacc[r];
        buf[mb + (q << 2) + r][24 + t] = f2bf(pacc[r]);
      }
    }

    // ---- slide window: 1 new element from buf ----
    const short nb = buf[cl][t + 6 + sub6];
    w0 = (w0 >> 16) | (w1 << 16);
    w1 = (w1 >> 16) | (w2 << 16);
    w2 = (w2 >> 16) | ((unsigned)(unsigned short)nb << 16);
  }
}

extern "C" void kernel_launch(void* const* d_in, const int* in_sizes, int n_in,
                              void* d_out, int out_size, void* d_ws, size_t ws_size,
                              hipStream_t stream) {
  (void)in_sizes; (void)n_in; (void)out_size; (void)ws_size;
  const float* pm25  = (const float*)d_in[0];
  const float* feat  = (const float*)d_in[1];
  // d_in[2] = time_feature (unused)
  const float* W_in  = (const float*)d_in[3];
  const float* b_in  = (const float*)d_in[4];
  const float* W_ih  = (const float*)d_in[5];
  const float* W_hh  = (const float*)d_in[6];
  const float* b_ih  = (const float*)d_in[7];
  const float* b_hh  = (const float*)d_in[8];
  const float* W_out = (const float*)d_in[9];
  const float* b_out = (const float*)d_in[10];
  float* ws  = (float*)d_ws;    // needs 128*48+128 floats = 25 KB
  float* out = (float*)d_out;

  setup_wc<<<dim3(25), dim3(256), 0, stream>>>(W_in, b_in, W_ih, b_ih, b_hh, ws);
  lstm_fused<<<dim3(CELLS / 64), dim3(256), 0, stream>>>(
      pm25, feat, W_hh, W_out, b_out, ws, out);
}